// Round 2
// baseline (646.441 us; speedup 1.0000x reference)
//
#include <hip/hip_runtime.h>
#include <hip/hip_bf16.h>
#include <math.h>

using bf16 = __hip_bfloat16;
typedef __attribute__((ext_vector_type(8))) short bf16x8;  // 8 bf16 = 4 VGPRs
typedef __attribute__((ext_vector_type(4))) float f32x4;

__device__ __forceinline__ float b2f(bf16 v) { return __bfloat162float(v); }
__device__ __forceinline__ bf16 f2b(float v) { return __float2bfloat16(v); }

// ---------------------------------------------------------------------------
// 128x128 GEMM core. A[M,K] K-major, B[N,K] K-major ("B^T" layout). BK=32.
// 256 threads = 4 waves; each wave owns a 64x64 quadrant as 4x4 16x16 tiles.
// Global operands may be f32 (converted to bf16 while staging) or bf16.
// ---------------------------------------------------------------------------

// Stage a [128 x 32] tile into LDS as bf16 row-major stride 32.
__device__ __forceinline__ void stage_tile(const bf16* __restrict__ g, int ldg,
                                           bf16* __restrict__ s) {
  int tid = threadIdx.x;
#pragma unroll
  for (int i = 0; i < 2; ++i) {
    int c = tid + i * 256;      // 512 chunks of 8 elements
    int row = c >> 2;
    int col = (c & 3) << 3;
    *(bf16x8*)(s + row * 32 + col) =
        *(const bf16x8*)(g + (size_t)row * ldg + col);
  }
}

__device__ __forceinline__ void stage_tile(const float* __restrict__ g, int ldg,
                                           bf16* __restrict__ s) {
  int tid = threadIdx.x;
#pragma unroll
  for (int i = 0; i < 2; ++i) {
    int c = tid + i * 256;
    int row = c >> 2;
    int col = (c & 3) << 3;
    const float4* gp = (const float4*)(g + (size_t)row * ldg + col);
    float4 v0 = gp[0];
    float4 v1 = gp[1];
    bf16 tmp[8] = {f2b(v0.x), f2b(v0.y), f2b(v0.z), f2b(v0.w),
                   f2b(v1.x), f2b(v1.y), f2b(v1.z), f2b(v1.w)};
    *(bf16x8*)(s + row * 32 + col) = *(bf16x8*)tmp;
  }
}

struct Acc { f32x4 a[4][4]; };

template <typename TA, typename TB>
__device__ __forceinline__ void gemm_core(const TA* __restrict__ A,
                                          const TB* __restrict__ B,
                                          int K, Acc& acc,
                                          bf16* sA, bf16* sB) {
  int lane = threadIdx.x & 63;
  int wave = threadIdx.x >> 6;
  int wm = wave & 1, wn = wave >> 1;
  int r = lane & 15;            // A/B operand: m (or n) = lane&15
  int ko = (lane >> 4) << 3;    // k = (lane>>4)*8 + j

  for (int k0 = 0; k0 < K; k0 += 32) {
    stage_tile(A + k0, K, sA);
    stage_tile(B + k0, K, sB);
    __syncthreads();
    bf16x8 af[4], bfr[4];
#pragma unroll
    for (int t = 0; t < 4; ++t) {
      af[t]  = *(const bf16x8*)(sA + (wm * 64 + t * 16 + r) * 32 + ko);
      bfr[t] = *(const bf16x8*)(sB + (wn * 64 + t * 16 + r) * 32 + ko);
    }
#pragma unroll
    for (int tm = 0; tm < 4; ++tm)
#pragma unroll
      for (int tn = 0; tn < 4; ++tn)
        acc.a[tm][tn] = __builtin_amdgcn_mfma_f32_16x16x32_bf16(
            af[tm], bfr[tn], acc.a[tm][tn], 0, 0, 0);
    __syncthreads();
  }
}

// Epilogue: C/D layout is col = lane&15, row = (lane>>4)*4 + reg (m89-verified)
template <typename TO, bool BIAS, bool GELU>
__device__ __forceinline__ void epilogue(const Acc& acc, TO* __restrict__ C,
                                         int ldc, const float* __restrict__ bias,
                                         float scale) {
  int lane = threadIdx.x & 63;
  int wave = threadIdx.x >> 6;
  int wm = wave & 1, wn = wave >> 1;
  int rbase = wm * 64 + ((lane >> 4) << 2);
  int cbase = wn * 64 + (lane & 15);
#pragma unroll
  for (int tm = 0; tm < 4; ++tm) {
#pragma unroll
    for (int tn = 0; tn < 4; ++tn) {
      int nn = cbase + tn * 16;
      float bv = BIAS ? bias[nn] : 0.0f;
#pragma unroll
      for (int rr = 0; rr < 4; ++rr) {
        int mm = rbase + tm * 16 + rr;
        float c = acc.a[tm][tn][rr] * scale + bv;
        if (GELU) c = 0.5f * c * (1.0f + erff(c * 0.70710678118f));
        if constexpr (__hip_internal::is_same<TO, bf16>::value)
          C[(size_t)mm * ldc + nn] = f2b(c);
        else
          C[(size_t)mm * ldc + nn] = c;
      }
    }
  }
}

// ---------------------------------------------------------------------------
// Kernel 1: QKV projection. z=0 -> Q, z=1 -> K, z=2 -> V stored transposed
// per batch: Vt[b][d][s]. X: [8192,1024] f32. W*: [1024,1024] f32.
// grid (64, 8, 3).
// ---------------------------------------------------------------------------
__global__ __launch_bounds__(256) void k_qkv(
    const float* __restrict__ X,
    const float* __restrict__ Wq, const float* __restrict__ Wk,
    const float* __restrict__ Wv,
    const float* __restrict__ bq, const float* __restrict__ bk,
    const float* __restrict__ bv,
    bf16* __restrict__ Q, bf16* __restrict__ Ko, bf16* __restrict__ Vt) {
  __shared__ alignas(16) bf16 sA[4096];
  __shared__ alignas(16) bf16 sB[4096];
  const int K = 1024, N = 1024;
  int z = blockIdx.z;
  const float* W    = (z == 0) ? Wq : (z == 1) ? Wk : Wv;
  const float* bias = (z == 0) ? bq : (z == 1) ? bk : bv;
  const float* A = X + (size_t)blockIdx.x * 128 * K;
  const float* B = W + (size_t)blockIdx.y * 128 * K;
  Acc acc = {};
  gemm_core(A, B, K, acc, sA, sB);

  if (z < 2) {
    bf16* C = (z == 0 ? Q : Ko) +
              (size_t)blockIdx.x * 128 * N + blockIdx.y * 128;
    epilogue<bf16, true, false>(acc, C, N, bias + blockIdx.y * 128, 1.0f);
  } else {
    int lane = threadIdx.x & 63;
    int wave = threadIdx.x >> 6;
    int wm = wave & 1, wn = wave >> 1;
    int rbase = blockIdx.x * 128 + wm * 64 + ((lane >> 4) << 2);
    int cbase = blockIdx.y * 128 + wn * 64 + (lane & 15);
#pragma unroll
    for (int tm = 0; tm < 4; ++tm)
#pragma unroll
      for (int tn = 0; tn < 4; ++tn) {
        int n = cbase + tn * 16;
        float bvv = bias[n];
#pragma unroll
        for (int rr = 0; rr < 4; ++rr) {
          int m = rbase + tm * 16 + rr;      // global token index
          int b = m >> 11, s = m & 2047;
          float c = acc.a[tm][tn][rr] + bvv;
          Vt[((size_t)b * 1024 + n) * 2048 + s] = f2b(c);
        }
      }
  }
}

// ---------------------------------------------------------------------------
// Kernel 2: scores = Q K^T * (1/sqrt(1024)), per batch. grid (16, 16, 4).
// Blocks fully above the causal diagonal are skipped (never read later).
// ---------------------------------------------------------------------------
__global__ __launch_bounds__(256) void k_scores(const bf16* __restrict__ Q,
                                                const bf16* __restrict__ Kk,
                                                bf16* __restrict__ P) {
  if (blockIdx.y > blockIdx.x) return;  // fully masked tile
  __shared__ alignas(16) bf16 sA[4096];
  __shared__ alignas(16) bf16 sB[4096];
  const int K = 1024, S = 2048;
  int z = blockIdx.z;
  const bf16* A = Q  + (size_t)z * S * K + (size_t)blockIdx.x * 128 * K;
  const bf16* B = Kk + (size_t)z * S * K + (size_t)blockIdx.y * 128 * K;
  Acc acc = {};
  gemm_core(A, B, K, acc, sA, sB);
  bf16* C = P + (size_t)z * S * S + (size_t)blockIdx.x * 128 * S +
            blockIdx.y * 128;
  epilogue<bf16, false, false>(acc, C, S, nullptr, 0.03125f);
}

// ---------------------------------------------------------------------------
// Kernel 3: causal softmax in-place on P rows. grid (2048, 4), 256 threads.
// Writes zeros for k > q so the PV GEMM needs no masking.
// ---------------------------------------------------------------------------
__global__ __launch_bounds__(256) void k_softmax(bf16* __restrict__ P) {
  const int S = 2048;
  int q = blockIdx.x, z = blockIdx.y;
  bf16* row = P + ((size_t)z * S + q) * S;
  __shared__ float red[4];
  int tid = threadIdx.x;

  float mx = -1e30f;
  for (int k = tid; k <= q; k += 256) mx = fmaxf(mx, b2f(row[k]));
#pragma unroll
  for (int o = 32; o > 0; o >>= 1) mx = fmaxf(mx, __shfl_xor(mx, o));
  if ((tid & 63) == 0) red[tid >> 6] = mx;
  __syncthreads();
  mx = fmaxf(fmaxf(red[0], red[1]), fmaxf(red[2], red[3]));
  __syncthreads();

  float sum = 0.0f;
  for (int k = tid; k <= q; k += 256) sum += expf(b2f(row[k]) - mx);
#pragma unroll
  for (int o = 32; o > 0; o >>= 1) sum += __shfl_xor(sum, o);
  if ((tid & 63) == 0) red[tid >> 6] = sum;
  __syncthreads();
  sum = red[0] + red[1] + red[2] + red[3];
  float inv = 1.0f / sum;

  for (int k = tid; k < S; k += 256) {
    float p = (k <= q) ? expf(b2f(row[k]) - mx) * inv : 0.0f;
    row[k] = f2b(p);
  }
}

// ---------------------------------------------------------------------------
// Kernel 4: attn = P @ V  (B operand = Vt, K-major). grid (16, 8, 4).
// ---------------------------------------------------------------------------
__global__ __launch_bounds__(256) void k_attn(const bf16* __restrict__ P,
                                              const bf16* __restrict__ Vt,
                                              bf16* __restrict__ O) {
  __shared__ alignas(16) bf16 sA[4096];
  __shared__ alignas(16) bf16 sB[4096];
  const int S = 2048, D = 1024;
  int z = blockIdx.z;
  const bf16* A = P  + (size_t)z * S * S + (size_t)blockIdx.x * 128 * S;
  const bf16* B = Vt + (size_t)z * D * S + (size_t)blockIdx.y * 128 * S;
  Acc acc = {};
  gemm_core(A, B, S, acc, sA, sB);
  bf16* C = O + (size_t)z * S * D + (size_t)blockIdx.x * 128 * D +
            blockIdx.y * 128;
  epilogue<bf16, false, false>(acc, C, D, nullptr, 1.0f);
}

// ---------------------------------------------------------------------------
// Kernel 5: out = attn @ Wo^T + bo. Wo f32 [1024,1024]. grid (64, 8).
// ---------------------------------------------------------------------------
__global__ __launch_bounds__(256) void k_out(const bf16* __restrict__ A0,
                                             const float* __restrict__ W,
                                             const float* __restrict__ bias,
                                             bf16* __restrict__ C0) {
  __shared__ alignas(16) bf16 sA[4096];
  __shared__ alignas(16) bf16 sB[4096];
  const int K = 1024, N = 1024;
  const bf16* A = A0 + (size_t)blockIdx.x * 128 * K;
  const float* B = W + (size_t)blockIdx.y * 128 * K;
  Acc acc = {};
  gemm_core(A, B, K, acc, sA, sB);
  bf16* C = C0 + (size_t)blockIdx.x * 128 * N + blockIdx.y * 128;
  epilogue<bf16, true, false>(acc, C, N, bias + blockIdx.y * 128, 1.0f);
}

// ---------------------------------------------------------------------------
// Kernel 6: ff = GELU(out @ Wf^T + bf) -> f32 d_out. Wf f32 [4096,1024].
// grid (64, 32).
// ---------------------------------------------------------------------------
__global__ __launch_bounds__(256) void k_ffn(const bf16* __restrict__ A0,
                                             const float* __restrict__ W,
                                             const float* __restrict__ bias,
                                             float* __restrict__ C0) {
  __shared__ alignas(16) bf16 sA[4096];
  __shared__ alignas(16) bf16 sB[4096];
  const int K = 1024, N = 4096;
  const bf16* A = A0 + (size_t)blockIdx.x * 128 * K;
  const float* B = W + (size_t)blockIdx.y * 128 * K;
  Acc acc = {};
  gemm_core(A, B, K, acc, sA, sB);
  float* C = C0 + (size_t)blockIdx.x * 128 * N + blockIdx.y * 128;
  epilogue<float, true, true>(acc, C, N, bias + blockIdx.y * 128, 1.0f);
}

// ---------------------------------------------------------------------------
extern "C" void kernel_launch(void* const* d_in, const int* in_sizes, int n_in,
                              void* d_out, int out_size, void* d_ws,
                              size_t ws_size, hipStream_t stream) {
  const float* x   = (const float*)d_in[0];
  const float* Wq  = (const float*)d_in[1];
  const float* bq  = (const float*)d_in[2];
  const float* Wk  = (const float*)d_in[3];
  const float* bk  = (const float*)d_in[4];
  const float* Wv  = (const float*)d_in[5];
  const float* bv  = (const float*)d_in[6];
  const float* Wo  = (const float*)d_in[7];
  const float* bo  = (const float*)d_in[8];
  const float* Wf  = (const float*)d_in[9];
  const float* bfb = (const float*)d_in[10];

  // Workspace layout (80 MB):
  //   [0,16M)   Q   (bf16)  -> reused as attn output
  //   [16,32M)  K   (bf16)  -> reused as out (post-Wo)
  //   [32,48M)  Vt  (bf16, 4 x [1024][2048])
  //   [48,80M)  P   (bf16, 4 x [2048][2048])
  char* ws = (char*)d_ws;
  bf16* Q    = (bf16*)(ws);
  bf16* Kb   = (bf16*)(ws + (size_t)(16 << 20));
  bf16* Vt   = (bf16*)(ws + (size_t)(32 << 20));
  bf16* P    = (bf16*)(ws + (size_t)(48 << 20));
  bf16* attn = Q;   // Q dead after k_scores
  bf16* out  = Kb;  // K dead after k_scores
  float* y   = (float*)d_out;

  k_qkv<<<dim3(64, 8, 3), 256, 0, stream>>>(x, Wq, Wk, Wv, bq, bk, bv,
                                            Q, Kb, Vt);
  k_scores<<<dim3(16, 16, 4), 256, 0, stream>>>(Q, Kb, P);
  k_softmax<<<dim3(2048, 4), 256, 0, stream>>>(P);
  k_attn<<<dim3(16, 8, 4), 256, 0, stream>>>(P, Vt, attn);
  k_out<<<dim3(64, 8), 256, 0, stream>>>(attn, Wo, bo, out);
  k_ffn<<<dim3(64, 32), 256, 0, stream>>>(out, Wf, bfb, y);
}

// Round 3
// 516.866 us; speedup vs baseline: 1.2507x; 1.2507x over previous
//
#include <hip/hip_runtime.h>
#include <hip/hip_bf16.h>
#include <math.h>

using bf16 = __hip_bfloat16;
typedef __attribute__((ext_vector_type(8))) short bf16x8;  // 8 bf16 = 4 VGPRs
typedef __attribute__((ext_vector_type(4))) short bf16x4;  // 4 bf16 = 2 VGPRs
typedef __attribute__((ext_vector_type(4))) float f32x4;

#define GLOBAL_AS __attribute__((address_space(1)))
#define LDS_AS __attribute__((address_space(3)))

__device__ __forceinline__ float b2f(bf16 v) { return __bfloat162float(v); }
__device__ __forceinline__ bf16 f2b(float v) { return __float2bfloat16(v); }

// ---------------------------------------------------------------------------
// f32 -> bf16 conversion, 4 elem/thread. n4 = n/4.
// ---------------------------------------------------------------------------
__global__ __launch_bounds__(256) void k_conv(const float* __restrict__ src,
                                              bf16* __restrict__ dst, int n4) {
  int i = blockIdx.x * 256 + threadIdx.x;
  if (i >= n4) return;
  float4 v = ((const float4*)src)[i];
  bf16 t[4] = {f2b(v.x), f2b(v.y), f2b(v.z), f2b(v.w)};
  *(bf16x4*)(dst + 4 * (size_t)i) = *(bf16x4*)t;
}

// ---------------------------------------------------------------------------
// m97-style async staging: one wave stages rows [w*32, w*32+32) of a
// [128 x 32] bf16 tile into LDS (row-major, stride 32) via two
// global_load_lds_dwordx4 (wave-uniform LDS base + lane*16).
// lane i -> row w*32 + (i>>2) (+16 for 2nd instr), col (i&3)*8.
// ---------------------------------------------------------------------------
__device__ __forceinline__ void stage_async(const bf16* __restrict__ g,
                                            int ldg, bf16* __restrict__ s) {
  int lane = threadIdx.x & 63;
  int wave = threadIdx.x >> 6;
  bf16* lds = s + wave * 1024;  // wave-uniform (2048 B per wave chunk)
  const bf16* g0 = g + (size_t)(wave * 32 + (lane >> 2)) * ldg + ((lane & 3) << 3);
  const bf16* g1 = g0 + (size_t)16 * ldg;
  __builtin_amdgcn_global_load_lds((GLOBAL_AS const unsigned*)g0,
                                   (LDS_AS unsigned*)lds, 16, 0, 0);
  __builtin_amdgcn_global_load_lds((GLOBAL_AS const unsigned*)g1,
                                   (LDS_AS unsigned*)(lds + 512), 16, 0, 0);
}

struct Acc { f32x4 a[4][4]; };

// 128x128 tile, A[M,K] K-major, B[N,K] K-major, BK=32, 4 waves, each wave a
// 64x64 quadrant as 4x4 MFMA 16x16x32 tiles.
__device__ __forceinline__ void gemm_core(const bf16* __restrict__ A,
                                          const bf16* __restrict__ B,
                                          int K, int lda, int ldb, Acc& acc,
                                          bf16* sA, bf16* sB) {
  int lane = threadIdx.x & 63;
  int wave = threadIdx.x >> 6;
  int wm = wave & 1, wn = wave >> 1;
  int r = lane & 15;            // operand row: m (or n) = lane&15
  int ko = (lane >> 4) << 3;    // k offset = (lane>>4)*8

  for (int k0 = 0; k0 < K; k0 += 32) {
    stage_async(A + k0, lda, sA);
    stage_async(B + k0, ldb, sB);
    __syncthreads();            // drains vmcnt -> LDS tiles visible
    bf16x8 af[4], bfr[4];
#pragma unroll
    for (int t = 0; t < 4; ++t) {
      af[t]  = *(const bf16x8*)(sA + (wm * 64 + t * 16 + r) * 32 + ko);
      bfr[t] = *(const bf16x8*)(sB + (wn * 64 + t * 16 + r) * 32 + ko);
    }
#pragma unroll
    for (int tm = 0; tm < 4; ++tm)
#pragma unroll
      for (int tn = 0; tn < 4; ++tn)
        acc.a[tm][tn] = __builtin_amdgcn_mfma_f32_16x16x32_bf16(
            af[tm], bfr[tn], acc.a[tm][tn], 0, 0, 0);
    __syncthreads();
  }
}

// Epilogue: C/D layout col = lane&15, row = (lane>>4)*4 + reg (m89-verified)
template <typename TO, bool BIAS, bool GELU>
__device__ __forceinline__ void epilogue(const Acc& acc, TO* __restrict__ C,
                                         int ldc, const float* __restrict__ bias,
                                         float scale) {
  int lane = threadIdx.x & 63;
  int wave = threadIdx.x >> 6;
  int wm = wave & 1, wn = wave >> 1;
  int rbase = wm * 64 + ((lane >> 4) << 2);
  int cbase = wn * 64 + (lane & 15);
#pragma unroll
  for (int tm = 0; tm < 4; ++tm) {
#pragma unroll
    for (int tn = 0; tn < 4; ++tn) {
      int nn = cbase + tn * 16;
      float bv = BIAS ? bias[nn] : 0.0f;
#pragma unroll
      for (int rr = 0; rr < 4; ++rr) {
        int mm = rbase + tm * 16 + rr;
        float c = acc.a[tm][tn][rr] * scale + bv;
        if (GELU) c = 0.5f * c * (1.0f + erff(c * 0.70710678118f));
        if constexpr (__hip_internal::is_same<TO, bf16>::value)
          C[(size_t)mm * ldc + nn] = f2b(c);
        else
          C[(size_t)mm * ldc + nn] = c;
      }
    }
  }
}

// ---------------------------------------------------------------------------
// Kernel 1: QKV. z=0->Q, z=1->K, z=2->V stored transposed per batch
// Vt[b][d][s]. Xb [8192,1024] bf16, W*b [1024,1024] bf16. grid (64,8,3).
// ---------------------------------------------------------------------------
__global__ __launch_bounds__(256) void k_qkv(
    const bf16* __restrict__ X, const bf16* __restrict__ Wq,
    const bf16* __restrict__ Wk, const bf16* __restrict__ Wv,
    const float* __restrict__ bq, const float* __restrict__ bk,
    const float* __restrict__ bv,
    bf16* __restrict__ Q, bf16* __restrict__ Ko, bf16* __restrict__ Vt) {
  __shared__ alignas(16) bf16 sA[4096];
  __shared__ alignas(16) bf16 sB[4096];
  const int K = 1024, N = 1024;
  int z = blockIdx.z;
  const bf16* W     = (z == 0) ? Wq : (z == 1) ? Wk : Wv;
  const float* bias = (z == 0) ? bq : (z == 1) ? bk : bv;
  const bf16* A = X + (size_t)blockIdx.x * 128 * K;
  const bf16* B = W + (size_t)blockIdx.y * 128 * K;
  Acc acc = {};
  gemm_core(A, B, K, K, K, acc, sA, sB);

  if (z < 2) {
    bf16* C = (z == 0 ? Q : Ko) +
              (size_t)blockIdx.x * 128 * N + blockIdx.y * 128;
    epilogue<bf16, true, false>(acc, C, N, bias + blockIdx.y * 128, 1.0f);
  } else {
    int lane = threadIdx.x & 63;
    int wave = threadIdx.x >> 6;
    int wm = wave & 1, wn = wave >> 1;
    int rbase = blockIdx.x * 128 + wm * 64 + ((lane >> 4) << 2);
    int cbase = blockIdx.y * 128 + wn * 64 + (lane & 15);
#pragma unroll
    for (int tm = 0; tm < 4; ++tm)
#pragma unroll
      for (int tn = 0; tn < 4; ++tn) {
        int n = cbase + tn * 16;
        float bvv = bias[n];
#pragma unroll
        for (int rr = 0; rr < 4; ++rr) {
          int m = rbase + tm * 16 + rr;      // global token index
          int b = m >> 11, s = m & 2047;
          float c = acc.a[tm][tn][rr] + bvv;
          Vt[((size_t)b * 1024 + n) * 2048 + s] = f2b(c);
        }
      }
  }
}

// ---------------------------------------------------------------------------
// Kernel 2: scores = Q K^T / 32 per batch. grid (16,16,4). bx remapped
// descending so heavy rows dispatch first; upper-triangle tiles skipped.
// ---------------------------------------------------------------------------
__global__ __launch_bounds__(256) void k_scores(const bf16* __restrict__ Q,
                                                const bf16* __restrict__ Kk,
                                                bf16* __restrict__ P) {
  int bx = 15 - blockIdx.x;
  if ((int)blockIdx.y > bx) return;  // fully masked tile (never read later)
  __shared__ alignas(16) bf16 sA[4096];
  __shared__ alignas(16) bf16 sB[4096];
  const int K = 1024, S = 2048;
  int z = blockIdx.z;
  const bf16* A = Q  + (size_t)z * S * K + (size_t)bx * 128 * K;
  const bf16* B = Kk + (size_t)z * S * K + (size_t)blockIdx.y * 128 * K;
  Acc acc = {};
  gemm_core(A, B, K, K, K, acc, sA, sB);
  bf16* C = P + (size_t)z * S * S + (size_t)bx * 128 * S + blockIdx.y * 128;
  epilogue<bf16, false, false>(acc, C, S, nullptr, 0.03125f);
}

// ---------------------------------------------------------------------------
// Kernel 3: causal softmax in-place on P rows. grid (2048,4). Zeros the
// masked tail only up to the next 128-multiple (k_attn reads no further).
// ---------------------------------------------------------------------------
__global__ __launch_bounds__(256) void k_softmax(bf16* __restrict__ P) {
  const int S = 2048;
  int q = blockIdx.x, z = blockIdx.y;
  bf16* row = P + ((size_t)z * S + q) * S;
  __shared__ float red[4];
  int tid = threadIdx.x;

  float mx = -1e30f;
  for (int k = tid; k <= q; k += 256) mx = fmaxf(mx, b2f(row[k]));
#pragma unroll
  for (int o = 32; o > 0; o >>= 1) mx = fmaxf(mx, __shfl_xor(mx, o));
  if ((tid & 63) == 0) red[tid >> 6] = mx;
  __syncthreads();
  mx = fmaxf(fmaxf(red[0], red[1]), fmaxf(red[2], red[3]));
  __syncthreads();

  float sum = 0.0f;
  for (int k = tid; k <= q; k += 256) sum += expf(b2f(row[k]) - mx);
#pragma unroll
  for (int o = 32; o > 0; o >>= 1) sum += __shfl_xor(sum, o);
  if ((tid & 63) == 0) red[tid >> 6] = sum;
  __syncthreads();
  sum = red[0] + red[1] + red[2] + red[3];
  float inv = 1.0f / sum;

  int kcap = ((q >> 7) + 1) << 7;  // k_attn never reads past this
  for (int k = tid; k < kcap; k += 256) {
    float p = (k <= q) ? expf(b2f(row[k]) - mx) * inv : 0.0f;
    row[k] = f2b(p);
  }
}

// ---------------------------------------------------------------------------
// Kernel 4: attn = P @ V (B = Vt, K-major). grid (16,8,4). Triangular:
// K-loop stops at (bx+1)*128; bx remapped descending for load balance.
// ---------------------------------------------------------------------------
__global__ __launch_bounds__(256) void k_attn(const bf16* __restrict__ P,
                                              const bf16* __restrict__ Vt,
                                              bf16* __restrict__ O) {
  __shared__ alignas(16) bf16 sA[4096];
  __shared__ alignas(16) bf16 sB[4096];
  const int S = 2048, D = 1024;
  int bx = 15 - (int)blockIdx.x;
  int z = blockIdx.z;
  int Keff = (bx + 1) * 128;
  const bf16* A = P  + (size_t)z * S * S + (size_t)bx * 128 * S;
  const bf16* B = Vt + (size_t)z * D * S + (size_t)blockIdx.y * 128 * S;
  Acc acc = {};
  gemm_core(A, B, Keff, S, S, acc, sA, sB);
  bf16* C = O + (size_t)z * S * D + (size_t)bx * 128 * D + blockIdx.y * 128;
  epilogue<bf16, false, false>(acc, C, D, nullptr, 1.0f);
}

// ---------------------------------------------------------------------------
// Kernel 5: out = attn @ Wo^T + bo (Wob bf16). grid (64,8).
// ---------------------------------------------------------------------------
__global__ __launch_bounds__(256) void k_out(const bf16* __restrict__ A0,
                                             const bf16* __restrict__ W,
                                             const float* __restrict__ bias,
                                             bf16* __restrict__ C0) {
  __shared__ alignas(16) bf16 sA[4096];
  __shared__ alignas(16) bf16 sB[4096];
  const int K = 1024, N = 1024;
  const bf16* A = A0 + (size_t)blockIdx.x * 128 * K;
  const bf16* B = W + (size_t)blockIdx.y * 128 * K;
  Acc acc = {};
  gemm_core(A, B, K, K, K, acc, sA, sB);
  bf16* C = C0 + (size_t)blockIdx.x * 128 * N + blockIdx.y * 128;
  epilogue<bf16, true, false>(acc, C, N, bias + blockIdx.y * 128, 1.0f);
}

// ---------------------------------------------------------------------------
// Kernel 6: ff = GELU(out @ Wf^T + bf) -> f32 d_out (Wfb bf16). grid (64,32).
// ---------------------------------------------------------------------------
__global__ __launch_bounds__(256) void k_ffn(const bf16* __restrict__ A0,
                                             const bf16* __restrict__ W,
                                             const float* __restrict__ bias,
                                             float* __restrict__ C0) {
  __shared__ alignas(16) bf16 sA[4096];
  __shared__ alignas(16) bf16 sB[4096];
  const int K = 1024, N = 4096;
  const bf16* A = A0 + (size_t)blockIdx.x * 128 * K;
  const bf16* B = W + (size_t)blockIdx.y * 128 * K;
  Acc acc = {};
  gemm_core(A, B, K, K, K, acc, sA, sB);
  float* C = C0 + (size_t)blockIdx.x * 128 * N + blockIdx.y * 128;
  epilogue<float, true, true>(acc, C, N, bias + blockIdx.y * 128, 1.0f);
}

// ---------------------------------------------------------------------------
// Workspace (80 MB), liveness-based reuse across the 5 x 16MB regions:
//   A [0,16):   xb (conv -> qkv)        | then P[0:16M)   (scores..attn)
//   B [16,32):  Wqb,Wkb,Wvb (6MB)       | then P[16M:32M)
//   C [32,48):  Q  (qkv -> scores)      | then attn (attn -> out)
//   D [48,64):  K  (qkv -> scores)      | then Wob(2MB)+Wfb(8MB) (conv after
//                                          scores -> out/ffn)
//   E [64,80):  Vt (qkv -> attn)        | then out (out -> ffn)
// ---------------------------------------------------------------------------
extern "C" void kernel_launch(void* const* d_in, const int* in_sizes, int n_in,
                              void* d_out, int out_size, void* d_ws,
                              size_t ws_size, hipStream_t stream) {
  const float* x   = (const float*)d_in[0];
  const float* Wq  = (const float*)d_in[1];
  const float* bq  = (const float*)d_in[2];
  const float* Wk  = (const float*)d_in[3];
  const float* bk  = (const float*)d_in[4];
  const float* Wv  = (const float*)d_in[5];
  const float* bv  = (const float*)d_in[6];
  const float* Wo  = (const float*)d_in[7];
  const float* bo  = (const float*)d_in[8];
  const float* Wf  = (const float*)d_in[9];
  const float* bfb = (const float*)d_in[10];

  char* ws = (char*)d_ws;
  const size_t MB = 1 << 20;
  bf16* xb   = (bf16*)(ws);                  // A
  bf16* Wqb  = (bf16*)(ws + 16 * MB);        // B
  bf16* Wkb  = (bf16*)(ws + 18 * MB);
  bf16* Wvb  = (bf16*)(ws + 20 * MB);
  bf16* P    = (bf16*)(ws);                  // A+B after qkv
  bf16* Q    = (bf16*)(ws + 32 * MB);        // C
  bf16* Kb   = (bf16*)(ws + 48 * MB);        // D
  bf16* Wob  = (bf16*)(ws + 48 * MB);        // D after scores
  bf16* Wfb  = (bf16*)(ws + 50 * MB);
  bf16* Vt   = (bf16*)(ws + 64 * MB);        // E
  bf16* attn = Q;                            // C after scores
  bf16* out  = Vt;                           // E after attn
  float* y   = (float*)d_out;

  k_conv<<<8192, 256, 0, stream>>>(x,  xb,  8192 * 1024 / 4);
  k_conv<<<1024, 256, 0, stream>>>(Wq, Wqb, 1024 * 1024 / 4);
  k_conv<<<1024, 256, 0, stream>>>(Wk, Wkb, 1024 * 1024 / 4);
  k_conv<<<1024, 256, 0, stream>>>(Wv, Wvb, 1024 * 1024 / 4);
  k_qkv<<<dim3(64, 8, 3), 256, 0, stream>>>(xb, Wqb, Wkb, Wvb, bq, bk, bv,
                                            Q, Kb, Vt);
  k_scores<<<dim3(16, 16, 4), 256, 0, stream>>>(Q, Kb, P);
  k_conv<<<1024, 256, 0, stream>>>(Wo, Wob, 1024 * 1024 / 4);
  k_conv<<<4096, 256, 0, stream>>>(Wf, Wfb, 4096 * 1024 / 4);
  k_softmax<<<dim3(2048, 4), 256, 0, stream>>>(P);
  k_attn<<<dim3(16, 8, 4), 256, 0, stream>>>(P, Vt, attn);
  k_out<<<dim3(64, 8), 256, 0, stream>>>(attn, Wob, bo, out);
  k_ffn<<<dim3(64, 32), 256, 0, stream>>>(out, Wfb, bfb, y);
}

// Round 4
// 508.311 us; speedup vs baseline: 1.2717x; 1.0168x over previous
//
#include <hip/hip_runtime.h>
#include <hip/hip_bf16.h>
#include <math.h>

using bf16 = __hip_bfloat16;
typedef __attribute__((ext_vector_type(8))) short bf16x8;  // 8 bf16 = 4 VGPRs
typedef __attribute__((ext_vector_type(4))) short bf16x4;  // 4 bf16 = 2 VGPRs
typedef __attribute__((ext_vector_type(4))) float f32x4;

#define GLOBAL_AS __attribute__((address_space(1)))
#define LDS_AS __attribute__((address_space(3)))

__device__ __forceinline__ float b2f(bf16 v) { return __bfloat162float(v); }
__device__ __forceinline__ bf16 f2b(float v) { return __float2bfloat16(v); }

// Fast exact-enough GELU: tanh form via hardware exp. |err| vs erf-GELU
// <= ~2e-4 absolute — far under the 1.13e-2 output threshold.
__device__ __forceinline__ float gelu_f(float x) {
  float u = x * (0.7978845608f + 0.0356774081f * x * x);
  float t = 1.0f - 2.0f / (1.0f + __expf(2.0f * u));
  return 0.5f * x * (1.0f + t);
}

// ---------------------------------------------------------------------------
// f32 -> bf16 conversion, 4 elem/thread. n4 = n/4.
// ---------------------------------------------------------------------------
__global__ __launch_bounds__(256) void k_conv(const float* __restrict__ src,
                                              bf16* __restrict__ dst, int n4) {
  int i = blockIdx.x * 256 + threadIdx.x;
  if (i >= n4) return;
  float4 v = ((const float4*)src)[i];
  bf16 t[4] = {f2b(v.x), f2b(v.y), f2b(v.z), f2b(v.w)};
  *(bf16x4*)(dst + 4 * (size_t)i) = *(bf16x4*)t;
}

// ---------------------------------------------------------------------------
// Async staging of one [128 x 32] bf16 sub-tile into LDS (row-major,
// stride 32) via global_load_lds_dwordx4, wave-uniform base + lane*16.
// ---------------------------------------------------------------------------
__device__ __forceinline__ void stage_async(const bf16* __restrict__ g,
                                            int ldg, bf16* __restrict__ s) {
  int lane = threadIdx.x & 63;
  int wave = threadIdx.x >> 6;
  bf16* lds = s + wave * 1024;  // 2048 B per wave chunk
  const bf16* g0 = g + (size_t)(wave * 32 + (lane >> 2)) * ldg + ((lane & 3) << 3);
  const bf16* g1 = g0 + (size_t)16 * ldg;
  __builtin_amdgcn_global_load_lds((GLOBAL_AS const unsigned*)g0,
                                   (LDS_AS unsigned*)lds, 16, 0, 0);
  __builtin_amdgcn_global_load_lds((GLOBAL_AS const unsigned*)g1,
                                   (LDS_AS unsigned*)(lds + 512), 16, 0, 0);
}

struct Acc { f32x4 a[4][4]; };

// 128x128 tile, A[M,K] K-major, B[N,K] K-major. BK=64 as two 32-col
// sub-tiles (keeps the verified stride-32 LDS layout) -> half the barriers.
// 4 waves; each wave owns a 64x64 quadrant as 4x4 MFMA 16x16x32 tiles.
__device__ __forceinline__ void gemm_core(const bf16* __restrict__ A,
                                          const bf16* __restrict__ B,
                                          int K, int lda, int ldb, Acc& acc,
                                          bf16* sA, bf16* sB) {
  int lane = threadIdx.x & 63;
  int wave = threadIdx.x >> 6;
  int wm = wave & 1, wn = wave >> 1;
  int r = lane & 15;            // operand row: m (or n) = lane&15
  int ko = (lane >> 4) << 3;    // k offset = (lane>>4)*8

  for (int k0 = 0; k0 < K; k0 += 64) {
    stage_async(A + k0,      lda, sA);
    stage_async(A + k0 + 32, lda, sA + 4096);
    stage_async(B + k0,      ldb, sB);
    stage_async(B + k0 + 32, ldb, sB + 4096);
    __syncthreads();            // drains vmcnt -> LDS tiles visible
#pragma unroll
    for (int kk = 0; kk < 2; ++kk) {
      bf16x8 af[4], bfr[4];
#pragma unroll
      for (int t = 0; t < 4; ++t) {
        af[t]  = *(const bf16x8*)(sA + kk * 4096 + (wm * 64 + t * 16 + r) * 32 + ko);
        bfr[t] = *(const bf16x8*)(sB + kk * 4096 + (wn * 64 + t * 16 + r) * 32 + ko);
      }
#pragma unroll
      for (int tm = 0; tm < 4; ++tm)
#pragma unroll
        for (int tn = 0; tn < 4; ++tn)
          acc.a[tm][tn] = __builtin_amdgcn_mfma_f32_16x16x32_bf16(
              af[tm], bfr[tn], acc.a[tm][tn], 0, 0, 0);
    }
    __syncthreads();
  }
}

// Epilogue: C/D layout col = lane&15, row = (lane>>4)*4 + reg (m89-verified)
template <typename TO, bool BIAS, bool GELU>
__device__ __forceinline__ void epilogue(const Acc& acc, TO* __restrict__ C,
                                         int ldc, const float* __restrict__ bias,
                                         float scale) {
  int lane = threadIdx.x & 63;
  int wave = threadIdx.x >> 6;
  int wm = wave & 1, wn = wave >> 1;
  int rbase = wm * 64 + ((lane >> 4) << 2);
  int cbase = wn * 64 + (lane & 15);
#pragma unroll
  for (int tm = 0; tm < 4; ++tm) {
#pragma unroll
    for (int tn = 0; tn < 4; ++tn) {
      int nn = cbase + tn * 16;
      float bv = BIAS ? bias[nn] : 0.0f;
#pragma unroll
      for (int rr = 0; rr < 4; ++rr) {
        int mm = rbase + tm * 16 + rr;
        float c = acc.a[tm][tn][rr] * scale + bv;
        if (GELU) c = gelu_f(c);
        if constexpr (__hip_internal::is_same<TO, bf16>::value)
          C[(size_t)mm * ldc + nn] = f2b(c);
        else
          C[(size_t)mm * ldc + nn] = c;
      }
    }
  }
}

// ---------------------------------------------------------------------------
// Kernel 1: QKV. z=0->Q, z=1->K, z=2->V stored transposed per batch
// Vt[b][d][s]. Xb [8192,1024] bf16, W*b [1024,1024] bf16. grid (64,8,3).
// z=2 epilogue: LDS transpose (padded stride 136) -> 16B coalesced stores.
// ---------------------------------------------------------------------------
__global__ __launch_bounds__(256) void k_qkv(
    const bf16* __restrict__ X, const bf16* __restrict__ Wq,
    const bf16* __restrict__ Wk, const bf16* __restrict__ Wv,
    const float* __restrict__ bq, const float* __restrict__ bk,
    const float* __restrict__ bv,
    bf16* __restrict__ Q, bf16* __restrict__ Ko, bf16* __restrict__ Vt) {
  __shared__ alignas(16) char arena[32768];
  bf16* sA = (bf16*)arena;
  bf16* sB = (bf16*)(arena + 16384);
  const int K = 1024, N = 1024;
  int z = blockIdx.z;
  const bf16* W     = (z == 0) ? Wq : (z == 1) ? Wk : Wv;
  const float* bias = (z == 0) ? bq : (z == 1) ? bk : bv;
  const bf16* A = X + (size_t)blockIdx.x * 128 * K;
  const bf16* B = W + (size_t)blockIdx.y * 128 * K;
  Acc acc = {};
  gemm_core(A, B, K, K, K, acc, sA, sB);

  if (z < 2) {
    bf16* C = (z == 0 ? Q : Ko) +
              (size_t)blockIdx.x * 128 * N + blockIdx.y * 128;
    epilogue<bf16, true, false>(acc, C, N, bias + blockIdx.y * 128, 1.0f);
  } else {
    // Transposed store: acc[mm=token s][nn=feature d] -> Vt[b][d][s]
    bf16* sT = (bf16*)arena;  // 64 x 136 bf16 = 17408 B (K-loop arena dead)
    int tid = threadIdx.x;
    int lane = tid & 63;
    int wave = tid >> 6;
    int wm = wave & 1, wn = wave >> 1;
    int b  = blockIdx.x >> 4;               // batch
    int s0 = (blockIdx.x & 15) * 128;       // seq base within batch
#pragma unroll
    for (int p = 0; p < 2; ++p) {           // 64 d-rows per pass
      __syncthreads();
      if (wn == p) {
        int rloc_s = wm * 64 + ((lane >> 4) << 2);   // local token
#pragma unroll
        for (int tn = 0; tn < 4; ++tn) {
          int nl = (lane & 15) + tn * 16;            // local d within pass
          float bvv = bias[blockIdx.y * 128 + p * 64 + nl];
#pragma unroll
          for (int tm = 0; tm < 4; ++tm)
#pragma unroll
            for (int rr = 0; rr < 4; ++rr)
              sT[nl * 136 + rloc_s + tm * 16 + rr] =
                  f2b(acc.a[tm][tn][rr] + bvv);
        }
      }
      __syncthreads();
      int c = tid & 15, r0 = tid >> 4;      // 16 col-chunks x 16 rows
#pragma unroll
      for (int j = 0; j < 4; ++j) {
        int rl = r0 + j * 16;               // local d row (0..63)
        int n = blockIdx.y * 128 + p * 64 + rl;
        *(bf16x8*)(Vt + ((size_t)b * 1024 + n) * 2048 + s0 + c * 8) =
            *(const bf16x8*)(sT + rl * 136 + c * 8);
      }
    }
  }
}

// ---------------------------------------------------------------------------
// Kernel 2: scores = Q K^T / 32 per batch. grid (16,16,4). bx remapped
// descending so heavy rows dispatch first; upper-triangle tiles skipped.
// ---------------------------------------------------------------------------
__global__ __launch_bounds__(256) void k_scores(const bf16* __restrict__ Q,
                                                const bf16* __restrict__ Kk,
                                                bf16* __restrict__ P) {
  int bx = 15 - blockIdx.x;
  if ((int)blockIdx.y > bx) return;  // fully masked tile (never read later)
  __shared__ alignas(16) char arena[32768];
  bf16* sA = (bf16*)arena;
  bf16* sB = (bf16*)(arena + 16384);
  const int K = 1024, S = 2048;
  int z = blockIdx.z;
  const bf16* A = Q  + (size_t)z * S * K + (size_t)bx * 128 * K;
  const bf16* B = Kk + (size_t)z * S * K + (size_t)blockIdx.y * 128 * K;
  Acc acc = {};
  gemm_core(A, B, K, K, K, acc, sA, sB);
  bf16* C = P + (size_t)z * S * S + (size_t)bx * 128 * S + blockIdx.y * 128;
  epilogue<bf16, false, false>(acc, C, S, nullptr, 0.03125f);
}

// ---------------------------------------------------------------------------
// Kernel 3: causal softmax in-place on P rows. grid (2048,4). Zeros the
// masked tail only up to the next 128-multiple (k_attn reads no further).
// ---------------------------------------------------------------------------
__global__ __launch_bounds__(256) void k_softmax(bf16* __restrict__ P) {
  const int S = 2048;
  int q = blockIdx.x, z = blockIdx.y;
  bf16* row = P + ((size_t)z * S + q) * S;
  __shared__ float red[4];
  int tid = threadIdx.x;

  float mx = -1e30f;
  for (int k = tid; k <= q; k += 256) mx = fmaxf(mx, b2f(row[k]));
#pragma unroll
  for (int o = 32; o > 0; o >>= 1) mx = fmaxf(mx, __shfl_xor(mx, o));
  if ((tid & 63) == 0) red[tid >> 6] = mx;
  __syncthreads();
  mx = fmaxf(fmaxf(red[0], red[1]), fmaxf(red[2], red[3]));
  __syncthreads();

  float sum = 0.0f;
  for (int k = tid; k <= q; k += 256) sum += __expf(b2f(row[k]) - mx);
#pragma unroll
  for (int o = 32; o > 0; o >>= 1) sum += __shfl_xor(sum, o);
  if ((tid & 63) == 0) red[tid >> 6] = sum;
  __syncthreads();
  sum = red[0] + red[1] + red[2] + red[3];
  float inv = 1.0f / sum;

  int kcap = ((q >> 7) + 1) << 7;  // k_attn never reads past this
  for (int k = tid; k < kcap; k += 256) {
    float p = (k <= q) ? __expf(b2f(row[k]) - mx) * inv : 0.0f;
    row[k] = f2b(p);
  }
}

// ---------------------------------------------------------------------------
// Kernel 4: attn = P @ V (B = Vt, K-major). grid (16,8,4). Triangular:
// K-loop stops at (bx+1)*128; bx remapped descending for load balance.
// ---------------------------------------------------------------------------
__global__ __launch_bounds__(256) void k_attn(const bf16* __restrict__ P,
                                              const bf16* __restrict__ Vt,
                                              bf16* __restrict__ O) {
  __shared__ alignas(16) char arena[32768];
  bf16* sA = (bf16*)arena;
  bf16* sB = (bf16*)(arena + 16384);
  const int S = 2048, D = 1024;
  int bx = 15 - (int)blockIdx.x;
  int z = blockIdx.z;
  int Keff = (bx + 1) * 128;
  const bf16* A = P  + (size_t)z * S * S + (size_t)bx * 128 * S;
  const bf16* B = Vt + (size_t)z * D * S + (size_t)blockIdx.y * 128 * S;
  Acc acc = {};
  gemm_core(A, B, Keff, S, S, acc, sA, sB);
  bf16* C = O + (size_t)z * S * D + (size_t)bx * 128 * D + blockIdx.y * 128;
  epilogue<bf16, false, false>(acc, C, D, nullptr, 1.0f);
}

// ---------------------------------------------------------------------------
// Kernel 5: out = attn @ Wo^T + bo (Wob bf16). grid (64,8).
// ---------------------------------------------------------------------------
__global__ __launch_bounds__(256) void k_out(const bf16* __restrict__ A0,
                                             const bf16* __restrict__ W,
                                             const float* __restrict__ bias,
                                             bf16* __restrict__ C0) {
  __shared__ alignas(16) char arena[32768];
  bf16* sA = (bf16*)arena;
  bf16* sB = (bf16*)(arena + 16384);
  const int K = 1024, N = 1024;
  const bf16* A = A0 + (size_t)blockIdx.x * 128 * K;
  const bf16* B = W + (size_t)blockIdx.y * 128 * K;
  Acc acc = {};
  gemm_core(A, B, K, K, K, acc, sA, sB);
  bf16* C = C0 + (size_t)blockIdx.x * 128 * N + blockIdx.y * 128;
  epilogue<bf16, true, false>(acc, C, N, bias + blockIdx.y * 128, 1.0f);
}

// ---------------------------------------------------------------------------
// Kernel 6: ff = GELU(out @ Wf^T + bf) -> f32 d_out (Wfb bf16). grid (64,32).
// ---------------------------------------------------------------------------
__global__ __launch_bounds__(256) void k_ffn(const bf16* __restrict__ A0,
                                             const bf16* __restrict__ W,
                                             const float* __restrict__ bias,
                                             float* __restrict__ C0) {
  __shared__ alignas(16) char arena[32768];
  bf16* sA = (bf16*)arena;
  bf16* sB = (bf16*)(arena + 16384);
  const int K = 1024, N = 4096;
  const bf16* A = A0 + (size_t)blockIdx.x * 128 * K;
  const bf16* B = W + (size_t)blockIdx.y * 128 * K;
  Acc acc = {};
  gemm_core(A, B, K, K, K, acc, sA, sB);
  float* C = C0 + (size_t)blockIdx.x * 128 * N + blockIdx.y * 128;
  epilogue<float, true, true>(acc, C, N, bias + blockIdx.y * 128, 1.0f);
}

// ---------------------------------------------------------------------------
// Workspace (80 MB), liveness-based reuse across the 5 x 16MB regions:
//   A [0,16):   xb (conv -> qkv)        | then P[0:16M)   (scores..attn)
//   B [16,32):  Wqb,Wkb,Wvb (6MB)       | then P[16M:32M)
//   C [32,48):  Q  (qkv -> scores)      | then attn (attn -> out)
//   D [48,64):  K  (qkv -> scores)      | then Wob(2MB)+Wfb(8MB)
//   E [64,80):  Vt (qkv -> attn)        | then out (out -> ffn)
// ---------------------------------------------------------------------------
extern "C" void kernel_launch(void* const* d_in, const int* in_sizes, int n_in,
                              void* d_out, int out_size, void* d_ws,
                              size_t ws_size, hipStream_t stream) {
  const float* x   = (const float*)d_in[0];
  const float* Wq  = (const float*)d_in[1];
  const float* bq  = (const float*)d_in[2];
  const float* Wk  = (const float*)d_in[3];
  const float* bk  = (const float*)d_in[4];
  const float* Wv  = (const float*)d_in[5];
  const float* bv  = (const float*)d_in[6];
  const float* Wo  = (const float*)d_in[7];
  const float* bo  = (const float*)d_in[8];
  const float* Wf  = (const float*)d_in[9];
  const float* bfb = (const float*)d_in[10];

  char* ws = (char*)d_ws;
  const size_t MB = 1 << 20;
  bf16* xb   = (bf16*)(ws);                  // A
  bf16* Wqb  = (bf16*)(ws + 16 * MB);        // B
  bf16* Wkb  = (bf16*)(ws + 18 * MB);
  bf16* Wvb  = (bf16*)(ws + 20 * MB);
  bf16* P    = (bf16*)(ws);                  // A+B after qkv
  bf16* Q    = (bf16*)(ws + 32 * MB);        // C
  bf16* Kb   = (bf16*)(ws + 48 * MB);        // D
  bf16* Wob  = (bf16*)(ws + 48 * MB);        // D after scores
  bf16* Wfb  = (bf16*)(ws + 50 * MB);
  bf16* Vt   = (bf16*)(ws + 64 * MB);        // E
  bf16* attn = Q;                            // C after scores
  bf16* out  = Vt;                           // E after attn
  float* y   = (float*)d_out;

  k_conv<<<8192, 256, 0, stream>>>(x,  xb,  8192 * 1024 / 4);
  k_conv<<<1024, 256, 0, stream>>>(Wq, Wqb, 1024 * 1024 / 4);
  k_conv<<<1024, 256, 0, stream>>>(Wk, Wkb, 1024 * 1024 / 4);
  k_conv<<<1024, 256, 0, stream>>>(Wv, Wvb, 1024 * 1024 / 4);
  k_qkv<<<dim3(64, 8, 3), 256, 0, stream>>>(xb, Wqb, Wkb, Wvb, bq, bk, bv,
                                            Q, Kb, Vt);
  k_scores<<<dim3(16, 16, 4), 256, 0, stream>>>(Q, Kb, P);
  k_conv<<<1024, 256, 0, stream>>>(Wo, Wob, 1024 * 1024 / 4);
  k_conv<<<4096, 256, 0, stream>>>(Wf, Wfb, 4096 * 1024 / 4);
  k_softmax<<<dim3(2048, 4), 256, 0, stream>>>(P);
  k_attn<<<dim3(16, 8, 4), 256, 0, stream>>>(P, Vt, attn);
  k_out<<<dim3(64, 8), 256, 0, stream>>>(attn, Wob, bo, out);
  k_ffn<<<dim3(64, 32), 256, 0, stream>>>(out, Wfb, bfb, y);
}

// Round 5
// 495.394 us; speedup vs baseline: 1.3049x; 1.0261x over previous
//
#include <hip/hip_runtime.h>
#include <hip/hip_bf16.h>
#include <math.h>

using bf16 = __hip_bfloat16;
typedef __attribute__((ext_vector_type(8))) short bf16x8;  // 8 bf16 = 4 VGPRs
typedef __attribute__((ext_vector_type(4))) short bf16x4;  // 4 bf16 = 2 VGPRs
typedef __attribute__((ext_vector_type(4))) float f32x4;

#define GLOBAL_AS __attribute__((address_space(1)))
#define LDS_AS __attribute__((address_space(3)))

__device__ __forceinline__ float b2f(bf16 v) { return __bfloat162float(v); }
__device__ __forceinline__ bf16 f2b(float v) { return __float2bfloat16(v); }
__device__ __forceinline__ float bs2f(short s) {
  union { unsigned u; float f; } x;
  x.u = ((unsigned)(unsigned short)s) << 16;
  return x.f;
}

// Fast GELU (tanh form via hw exp): |err| vs erf-GELU <= ~2e-4 absolute.
__device__ __forceinline__ float gelu_f(float x) {
  float u = x * (0.7978845608f + 0.0356774081f * x * x);
  float t = 1.0f - 2.0f / (1.0f + __expf(2.0f * u));
  return 0.5f * x * (1.0f + t);
}

// ---------------------------------------------------------------------------
// Fused f32->bf16 conversion for x, Wq, Wk, Wv. 4 elem/thread.
// blocks: x 8192 | Wq 1024 | Wk 1024 | Wv 1024  (grid 11264)
// ---------------------------------------------------------------------------
__global__ __launch_bounds__(256) void k_conv4(
    const float* __restrict__ x, const float* __restrict__ Wq,
    const float* __restrict__ Wk, const float* __restrict__ Wv,
    bf16* __restrict__ xb, bf16* __restrict__ Wqb,
    bf16* __restrict__ Wkb, bf16* __restrict__ Wvb) {
  int bid = blockIdx.x;
  const float* src;
  bf16* dst;
  int local;
  if (bid < 8192) { src = x; dst = xb; local = bid; }
  else {
    int b2 = bid - 8192;
    int w = b2 >> 10;
    local = b2 & 1023;
    src = (w == 0) ? Wq : (w == 1) ? Wk : Wv;
    dst = (w == 0) ? Wqb : (w == 1) ? Wkb : Wvb;
  }
  int i = local * 256 + threadIdx.x;
  float4 v = ((const float4*)src)[i];
  bf16 t[4] = {f2b(v.x), f2b(v.y), f2b(v.z), f2b(v.w)};
  *(bf16x4*)(dst + 4 * (size_t)i) = *(bf16x4*)t;
}

// Fused conversion for Wo (1024 blocks) + Wf (4096 blocks). grid 5120.
__global__ __launch_bounds__(256) void k_conv2(
    const float* __restrict__ Wo, const float* __restrict__ Wf,
    bf16* __restrict__ Wob, bf16* __restrict__ Wfb) {
  int bid = blockIdx.x;
  const float* src = (bid < 1024) ? Wo : Wf;
  bf16* dst = (bid < 1024) ? Wob : Wfb;
  int local = (bid < 1024) ? bid : bid - 1024;
  int i = local * 256 + threadIdx.x;
  float4 v = ((const float4*)src)[i];
  bf16 t[4] = {f2b(v.x), f2b(v.y), f2b(v.z), f2b(v.w)};
  *(bf16x4*)(dst + 4 * (size_t)i) = *(bf16x4*)t;
}

// ---------------------------------------------------------------------------
// Async staging of one [128 x 32] bf16 tile into LDS (row-major, stride 32)
// via global_load_lds_dwordx4, wave-uniform base + lane*16.
// ---------------------------------------------------------------------------
__device__ __forceinline__ void stage_async(const bf16* __restrict__ g,
                                            int ldg, bf16* __restrict__ s) {
  int lane = threadIdx.x & 63;
  int wave = threadIdx.x >> 6;
  bf16* lds = s + wave * 1024;  // 2048 B per wave chunk
  const bf16* g0 = g + (size_t)(wave * 32 + (lane >> 2)) * ldg + ((lane & 3) << 3);
  const bf16* g1 = g0 + (size_t)16 * ldg;
  __builtin_amdgcn_global_load_lds((GLOBAL_AS const unsigned*)g0,
                                   (LDS_AS unsigned*)lds, 16, 0, 0);
  __builtin_amdgcn_global_load_lds((GLOBAL_AS const unsigned*)g1,
                                   (LDS_AS unsigned*)(lds + 512), 16, 0, 0);
}

struct Acc { f32x4 a[4][4]; };

// 128x128 tile, A[M,K] K-major, B[N,K] K-major, BK=32, 4 waves, each wave a
// 64x64 quadrant as 4x4 MFMA 16x16x32 tiles.  (m97 structure; BK=64 was
// measured regression: LDS 32KB cut blocks/CU 8->5, VALUBusy 25->49%.)
__device__ __forceinline__ void gemm_core(const bf16* __restrict__ A,
                                          const bf16* __restrict__ B,
                                          int K, int lda, int ldb, Acc& acc,
                                          bf16* sA, bf16* sB) {
  int lane = threadIdx.x & 63;
  int wave = threadIdx.x >> 6;
  int wm = wave & 1, wn = wave >> 1;
  int r = lane & 15;            // operand row: m (or n) = lane&15
  int ko = (lane >> 4) << 3;    // k offset = (lane>>4)*8

  for (int k0 = 0; k0 < K; k0 += 32) {
    stage_async(A + k0, lda, sA);
    stage_async(B + k0, ldb, sB);
    __syncthreads();            // drains vmcnt -> LDS tiles visible
    bf16x8 af[4], bfr[4];
#pragma unroll
    for (int t = 0; t < 4; ++t) {
      af[t]  = *(const bf16x8*)(sA + (wm * 64 + t * 16 + r) * 32 + ko);
      bfr[t] = *(const bf16x8*)(sB + (wn * 64 + t * 16 + r) * 32 + ko);
    }
#pragma unroll
    for (int tm = 0; tm < 4; ++tm)
#pragma unroll
      for (int tn = 0; tn < 4; ++tn)
        acc.a[tm][tn] = __builtin_amdgcn_mfma_f32_16x16x32_bf16(
            af[tm], bfr[tn], acc.a[tm][tn], 0, 0, 0);
    __syncthreads();
  }
}

// Epilogue: C/D layout col = lane&15, row = (lane>>4)*4 + reg (m89-verified)
template <typename TO, bool BIAS, bool GELU>
__device__ __forceinline__ void epilogue(const Acc& acc, TO* __restrict__ C,
                                         int ldc, const float* __restrict__ bias,
                                         float scale) {
  int lane = threadIdx.x & 63;
  int wave = threadIdx.x >> 6;
  int wm = wave & 1, wn = wave >> 1;
  int rbase = wm * 64 + ((lane >> 4) << 2);
  int cbase = wn * 64 + (lane & 15);
#pragma unroll
  for (int tm = 0; tm < 4; ++tm) {
#pragma unroll
    for (int tn = 0; tn < 4; ++tn) {
      int nn = cbase + tn * 16;
      float bv = BIAS ? bias[nn] : 0.0f;
#pragma unroll
      for (int rr = 0; rr < 4; ++rr) {
        int mm = rbase + tm * 16 + rr;
        float c = acc.a[tm][tn][rr] * scale + bv;
        if (GELU) c = gelu_f(c);
        if constexpr (__hip_internal::is_same<TO, bf16>::value)
          C[(size_t)mm * ldc + nn] = f2b(c);
        else
          C[(size_t)mm * ldc + nn] = c;
      }
    }
  }
}

// ---------------------------------------------------------------------------
// Kernel 1: QKV. z=0->Q, z=1->K, z=2->V stored transposed per batch
// Vt[b][d][s]. grid (64,8,3). z=2: LDS transpose (stride 136) -> 16B stores.
// ---------------------------------------------------------------------------
__global__ __launch_bounds__(256) void k_qkv(
    const bf16* __restrict__ X, const bf16* __restrict__ Wq,
    const bf16* __restrict__ Wk, const bf16* __restrict__ Wv,
    const float* __restrict__ bq, const float* __restrict__ bk,
    const float* __restrict__ bv,
    bf16* __restrict__ Q, bf16* __restrict__ Ko, bf16* __restrict__ Vt) {
  __shared__ alignas(16) char arena[17408];  // 16KB GEMM | 17.4KB transpose
  bf16* sA = (bf16*)arena;
  bf16* sB = (bf16*)(arena + 8192);
  const int K = 1024, N = 1024;
  int z = blockIdx.z;
  const bf16* W     = (z == 0) ? Wq : (z == 1) ? Wk : Wv;
  const float* bias = (z == 0) ? bq : (z == 1) ? bk : bv;
  const bf16* A = X + (size_t)blockIdx.x * 128 * K;
  const bf16* B = W + (size_t)blockIdx.y * 128 * K;
  Acc acc = {};
  gemm_core(A, B, K, K, K, acc, sA, sB);

  if (z < 2) {
    bf16* C = (z == 0 ? Q : Ko) +
              (size_t)blockIdx.x * 128 * N + blockIdx.y * 128;
    epilogue<bf16, true, false>(acc, C, N, bias + blockIdx.y * 128, 1.0f);
  } else {
    // Transposed store: acc[mm=token s][nn=feature d] -> Vt[b][d][s]
    bf16* sT = (bf16*)arena;  // 64 x 136 bf16 = 17408 B (GEMM arena dead)
    int tid = threadIdx.x;
    int lane = tid & 63;
    int wave = tid >> 6;
    int wm = wave & 1, wn = wave >> 1;
    int b  = blockIdx.x >> 4;               // batch
    int s0 = (blockIdx.x & 15) * 128;       // seq base within batch
#pragma unroll
    for (int p = 0; p < 2; ++p) {           // 64 d-rows per pass
      __syncthreads();
      if (wn == p) {
        int rloc_s = wm * 64 + ((lane >> 4) << 2);   // local token
#pragma unroll
        for (int tn = 0; tn < 4; ++tn) {
          int nl = (lane & 15) + tn * 16;            // local d within pass
          float bvv = bias[blockIdx.y * 128 + p * 64 + nl];
#pragma unroll
          for (int tm = 0; tm < 4; ++tm)
#pragma unroll
            for (int rr = 0; rr < 4; ++rr)
              sT[nl * 136 + rloc_s + tm * 16 + rr] =
                  f2b(acc.a[tm][tn][rr] + bvv);
        }
      }
      __syncthreads();
      int c = tid & 15, r0 = tid >> 4;      // 16 col-chunks x 16 rows
#pragma unroll
      for (int j = 0; j < 4; ++j) {
        int rl = r0 + j * 16;               // local d row (0..63)
        int n = blockIdx.y * 128 + p * 64 + rl;
        *(bf16x8*)(Vt + ((size_t)b * 1024 + n) * 2048 + s0 + c * 8) =
            *(const bf16x8*)(sT + rl * 136 + c * 8);
      }
    }
  }
}

// ---------------------------------------------------------------------------
// Kernel 2: scores = Q K^T / 32 per batch. grid (16,16,4). bx remapped
// descending so heavy rows dispatch first; upper-triangle tiles skipped.
// ---------------------------------------------------------------------------
__global__ __launch_bounds__(256) void k_scores(const bf16* __restrict__ Q,
                                                const bf16* __restrict__ Kk,
                                                bf16* __restrict__ P) {
  int bx = 15 - blockIdx.x;
  if ((int)blockIdx.y > bx) return;  // fully masked tile (never read later)
  __shared__ alignas(16) char arena[16384];
  bf16* sA = (bf16*)arena;
  bf16* sB = (bf16*)(arena + 8192);
  const int K = 1024, S = 2048;
  int z = blockIdx.z;
  const bf16* A = Q  + (size_t)z * S * K + (size_t)bx * 128 * K;
  const bf16* B = Kk + (size_t)z * S * K + (size_t)blockIdx.y * 128 * K;
  Acc acc = {};
  gemm_core(A, B, K, K, K, acc, sA, sB);
  bf16* C = P + (size_t)z * S * S + (size_t)bx * 128 * S + blockIdx.y * 128;
  epilogue<bf16, false, false>(acc, C, S, nullptr, 0.03125f);
}

// ---------------------------------------------------------------------------
// Kernel 3: causal softmax in-place on P rows. grid (2048,4). bf16x8
// vectorized; zeros masked tail up to next 128-multiple (k_attn's cap).
// ---------------------------------------------------------------------------
__global__ __launch_bounds__(256) void k_softmax(bf16* __restrict__ P) {
  const int S = 2048;
  int q = blockIdx.x, z = blockIdx.y;
  bf16* row = P + ((size_t)z * S + q) * S;
  __shared__ float red[4];
  int tid = threadIdx.x;
  int kcap = ((q >> 7) + 1) << 7;  // k_attn never reads past this
  int nch = kcap >> 3;             // 8-elem chunks (kcap % 8 == 0)

  float mx = -1e30f;
  for (int c = tid; c < nch; c += 256) {
    int k = c << 3;
    bf16x8 v = *(const bf16x8*)(row + k);
#pragma unroll
    for (int j = 0; j < 8; ++j)
      if (k + j <= q) mx = fmaxf(mx, bs2f(v[j]));
  }
#pragma unroll
  for (int o = 32; o > 0; o >>= 1) mx = fmaxf(mx, __shfl_xor(mx, o));
  if ((tid & 63) == 0) red[tid >> 6] = mx;
  __syncthreads();
  mx = fmaxf(fmaxf(red[0], red[1]), fmaxf(red[2], red[3]));
  __syncthreads();

  float sum = 0.0f;
  for (int c = tid; c < nch; c += 256) {
    int k = c << 3;
    bf16x8 v = *(const bf16x8*)(row + k);
#pragma unroll
    for (int j = 0; j < 8; ++j)
      if (k + j <= q) sum += __expf(bs2f(v[j]) - mx);
  }
#pragma unroll
  for (int o = 32; o > 0; o >>= 1) sum += __shfl_xor(sum, o);
  if ((tid & 63) == 0) red[tid >> 6] = sum;
  __syncthreads();
  sum = red[0] + red[1] + red[2] + red[3];
  float inv = 1.0f / sum;

  for (int c = tid; c < nch; c += 256) {
    int k = c << 3;
    bf16x8 v = *(const bf16x8*)(row + k);
    bf16 t[8];
#pragma unroll
    for (int j = 0; j < 8; ++j) {
      float p = (k + j <= q) ? __expf(bs2f(v[j]) - mx) * inv : 0.0f;
      t[j] = f2b(p);
    }
    *(bf16x8*)(row + k) = *(bf16x8*)t;
  }
}

// ---------------------------------------------------------------------------
// Kernel 4: attn = P @ V (B = Vt, K-major). grid (16,8,4). Triangular:
// K-loop stops at (bx+1)*128; bx remapped descending for load balance.
// ---------------------------------------------------------------------------
__global__ __launch_bounds__(256) void k_attn(const bf16* __restrict__ P,
                                              const bf16* __restrict__ Vt,
                                              bf16* __restrict__ O) {
  __shared__ alignas(16) char arena[16384];
  bf16* sA = (bf16*)arena;
  bf16* sB = (bf16*)(arena + 8192);
  const int S = 2048, D = 1024;
  int bx = 15 - (int)blockIdx.x;
  int z = blockIdx.z;
  int Keff = (bx + 1) * 128;
  const bf16* A = P  + (size_t)z * S * S + (size_t)bx * 128 * S;
  const bf16* B = Vt + (size_t)z * D * S + (size_t)blockIdx.y * 128 * S;
  Acc acc = {};
  gemm_core(A, B, Keff, S, S, acc, sA, sB);
  bf16* C = O + (size_t)z * S * D + (size_t)bx * 128 * D + blockIdx.y * 128;
  epilogue<bf16, false, false>(acc, C, D, nullptr, 1.0f);
}

// ---------------------------------------------------------------------------
// Kernel 5: out = attn @ Wo^T + bo (Wob bf16). grid (64,8).
// ---------------------------------------------------------------------------
__global__ __launch_bounds__(256) void k_out(const bf16* __restrict__ A0,
                                             const bf16* __restrict__ W,
                                             const float* __restrict__ bias,
                                             bf16* __restrict__ C0) {
  __shared__ alignas(16) char arena[16384];
  bf16* sA = (bf16*)arena;
  bf16* sB = (bf16*)(arena + 8192);
  const int K = 1024, N = 1024;
  const bf16* A = A0 + (size_t)blockIdx.x * 128 * K;
  const bf16* B = W + (size_t)blockIdx.y * 128 * K;
  Acc acc = {};
  gemm_core(A, B, K, K, K, acc, sA, sB);
  bf16* C = C0 + (size_t)blockIdx.x * 128 * N + blockIdx.y * 128;
  epilogue<bf16, true, false>(acc, C, N, bias + blockIdx.y * 128, 1.0f);
}

// ---------------------------------------------------------------------------
// Kernel 6: ff = GELU(out @ Wf^T + bf) -> f32 d_out (Wfb bf16). grid (64,32).
// ---------------------------------------------------------------------------
__global__ __launch_bounds__(256) void k_ffn(const bf16* __restrict__ A0,
                                             const bf16* __restrict__ W,
                                             const float* __restrict__ bias,
                                             float* __restrict__ C0) {
  __shared__ alignas(16) char arena[16384];
  bf16* sA = (bf16*)arena;
  bf16* sB = (bf16*)(arena + 8192);
  const int K = 1024, N = 4096;
  const bf16* A = A0 + (size_t)blockIdx.x * 128 * K;
  const bf16* B = W + (size_t)blockIdx.y * 128 * K;
  Acc acc = {};
  gemm_core(A, B, K, K, K, acc, sA, sB);
  float* C = C0 + (size_t)blockIdx.x * 128 * N + blockIdx.y * 128;
  epilogue<float, true, true>(acc, C, N, bias + blockIdx.y * 128, 1.0f);
}

// ---------------------------------------------------------------------------
// Workspace (80 MB), liveness-based reuse across the 5 x 16MB regions:
//   A [0,16):   xb (conv -> qkv)        | then P[0:16M)   (scores..attn)
//   B [16,32):  Wqb,Wkb,Wvb (6MB)       | then P[16M:32M)
//   C [32,48):  Q  (qkv -> scores)      | then attn (attn -> out)
//   D [48,64):  K  (qkv -> scores)      | then Wob(2MB)+Wfb(8MB)
//   E [64,80):  Vt (qkv -> attn)        | then out (out -> ffn)
// ---------------------------------------------------------------------------
extern "C" void kernel_launch(void* const* d_in, const int* in_sizes, int n_in,
                              void* d_out, int out_size, void* d_ws,
                              size_t ws_size, hipStream_t stream) {
  const float* x   = (const float*)d_in[0];
  const float* Wq  = (const float*)d_in[1];
  const float* bq  = (const float*)d_in[2];
  const float* Wk  = (const float*)d_in[3];
  const float* bk  = (const float*)d_in[4];
  const float* Wv  = (const float*)d_in[5];
  const float* bv  = (const float*)d_in[6];
  const float* Wo  = (const float*)d_in[7];
  const float* bo  = (const float*)d_in[8];
  const float* Wf  = (const float*)d_in[9];
  const float* bfb = (const float*)d_in[10];

  char* ws = (char*)d_ws;
  const size_t MB = 1 << 20;
  bf16* xb   = (bf16*)(ws);                  // A
  bf16* Wqb  = (bf16*)(ws + 16 * MB);        // B
  bf16* Wkb  = (bf16*)(ws + 18 * MB);
  bf16* Wvb  = (bf16*)(ws + 20 * MB);
  bf16* P    = (bf16*)(ws);                  // A+B after qkv
  bf16* Q    = (bf16*)(ws + 32 * MB);        // C
  bf16* Kb   = (bf16*)(ws + 48 * MB);        // D
  bf16* Wob  = (bf16*)(ws + 48 * MB);        // D after scores
  bf16* Wfb  = (bf16*)(ws + 50 * MB);
  bf16* Vt   = (bf16*)(ws + 64 * MB);        // E
  bf16* attn = Q;                            // C after scores
  bf16* out  = Vt;                           // E after attn
  float* y   = (float*)d_out;

  k_conv4<<<11264, 256, 0, stream>>>(x, Wq, Wk, Wv, xb, Wqb, Wkb, Wvb);
  k_qkv<<<dim3(64, 8, 3), 256, 0, stream>>>(xb, Wqb, Wkb, Wvb, bq, bk, bv,
                                            Q, Kb, Vt);
  k_scores<<<dim3(16, 16, 4), 256, 0, stream>>>(Q, Kb, P);
  k_conv2<<<5120, 256, 0, stream>>>(Wo, Wf, Wob, Wfb);
  k_softmax<<<dim3(2048, 4), 256, 0, stream>>>(P);
  k_attn<<<dim3(16, 8, 4), 256, 0, stream>>>(P, Vt, attn);
  k_out<<<dim3(64, 8), 256, 0, stream>>>(attn, Wob, bo, out);
  k_ffn<<<dim3(64, 32), 256, 0, stream>>>(out, Wfb, bfb, y);
}